// Round 1
// baseline (4574.138 us; speedup 1.0000x reference)
//
#include <hip/hip_runtime.h>
#include <hip/hip_bf16.h>

// Swin-3D block, fp32 SIMT baseline.
// B=2, C=96, D=32, H=64, W=64, WS=4, SHIFT=2, HEADS=4, hd=24
// tokens T = 262144, windows Bn = 4096, N = 64 tokens/window.

typedef unsigned int uint32;

__device__ __forceinline__ float bf_lo(uint32 u) { return __uint_as_float(u << 16); }
__device__ __forceinline__ float bf_hi(uint32 u) { return __uint_as_float(u & 0xffff0000u); }

// ---------------------------------------------------------------- K1
// LN1 + roll(-2,-2,-2) + 4x4x4 window partition.
// grid 4096 = b*2048 + d*64 + h ; block 256 handles the 64 w-tokens.
__global__ __launch_bounds__(256) void k1_ln_part(
    const float* __restrict__ x, const float* __restrict__ g1,
    const float* __restrict__ b1, float* __restrict__ xw)
{
  __shared__ float sX[64 * 97];
  int blk = blockIdx.x;
  int b = blk >> 11;
  int d = (blk >> 6) & 31;
  int h = blk & 63;
  int tid = threadIdx.x;
  int base = (b * 96 * 32 + d) * 4096 + h * 64;   // + c*131072 + w
  #pragma unroll
  for (int it = 0; it < 24; ++it) {
    int idx = it * 256 + tid;
    int c = idx >> 6;
    int w = idx & 63;
    sX[w * 97 + c] = x[base + c * 131072 + w];
  }
  __syncthreads();
  int t = tid >> 2, gq = tid & 3;   // 4 lanes per token
  float s1 = 0.f, s2 = 0.f;
  #pragma unroll
  for (int k = 0; k < 24; ++k) {
    float v = sX[t * 97 + gq + 4 * k];
    s1 += v; s2 += v * v;
  }
  s1 += __shfl_xor(s1, 1); s1 += __shfl_xor(s1, 2);
  s2 += __shfl_xor(s2, 1); s2 += __shfl_xor(s2, 2);
  float mean = s1 * (1.0f / 96.0f);
  float var  = s2 * (1.0f / 96.0f) - mean * mean;
  float rstd = rsqrtf(var + 1e-5f);
  // rolled coords -> window id / local token id
  int dr = (d + 30) & 31, hr = (h + 62) & 63, wr = (t + 62) & 63;
  int widx = ((dr >> 2) << 8) | ((hr >> 2) << 4) | (wr >> 2);
  int n    = ((dr & 3) << 4) | ((hr & 3) << 2) | (wr & 3);
  int obase = (b * 2048 + widx) * 6144 + n * 96;
  #pragma unroll
  for (int k = 0; k < 24; ++k) {
    int c = gq + 4 * k;
    xw[obase + c] = (sX[t * 97 + c] - mean) * rstd * g1[c] + b1[c];
  }
}

// ---------------------------------------------------------------- K2
// Per-window fused: QKV -> (per head) scores + rel-pos bias + shift mask
// -> softmax -> PV -> proj.  grid 4096 windows, block 256.
__global__ __launch_bounds__(256) void k2_attn(
    const float* __restrict__ xw, const float* __restrict__ qkvw,
    const float* __restrict__ qkvb, const float* __restrict__ rpb,
    const float* __restrict__ projw, const float* __restrict__ projb,
    float* __restrict__ yw)
{
  __shared__ float sX[64 * 97];     // xw tile (later reused for proj result)
  __shared__ float sU[8960];        // sQ|sK|sV|sS ; later overlaid by sO
  __shared__ int slab[64];
  float* sQ = sU;                   // [64][25]
  float* sK = sU + 1600;            // [64][25]
  float* sV = sU + 3200;            // [64][25]
  float* sS = sU + 4800;            // [64][65]

  int bn = blockIdx.x;
  int widx = bn & 2047;
  int tid = threadIdx.x;
  int lane = tid & 63;
  int wv = tid >> 6;

  const float* xrow = xw + bn * 6144;
  #pragma unroll
  for (int it = 0; it < 24; ++it) {
    int idx = it * 256 + tid;
    int t = idx / 96;
    int c = idx - t * 96;
    sX[t * 97 + c] = xrow[idx];
  }
  if (tid < 64) {
    // shift-mask labels (analytic _MASK): boundary windows only
    int dw = widx >> 8, hw = (widx >> 4) & 15, ww = widx & 15;
    int d1 = tid >> 4, e1 = (tid >> 2) & 3, w1 = tid & 3;
    int ld = (dw == 7)  ? ((d1 >> 1) + 1) : 0;
    int lh = (hw == 15) ? ((e1 >> 1) + 1) : 0;
    int lw = (ww == 15) ? ((w1 >> 1) + 1) : 0;
    slab[tid] = ld * 9 + lh * 3 + lw;
  }
  __syncthreads();

  float Oreg[24];                   // O[i][hh*6..] for i = tid>>2, dgrp = tid&3
  const float qscale = 0.20412414523193154f;   // 24^-0.5

  #pragma unroll
  for (int hh = 0; hh < 4; ++hh) {
    // ---- QKV for this head: thread owns token t=lane, 18 out channels ----
    int wrs[18];
    #pragma unroll
    for (int r = 0; r < 18; ++r)
      wrs[r] = (r < 6)  ? (hh * 24 + wv + 4 * r)
             : (r < 12) ? (96 + hh * 24 + wv + 4 * (r - 6))
                        : (192 + hh * 24 + wv + 4 * (r - 12));
    float a[18];
    #pragma unroll
    for (int r = 0; r < 18; ++r) a[r] = qkvb[wrs[r]];
    #pragma unroll 3
    for (int kk = 0; kk < 24; ++kk) {
      float x0 = sX[lane * 97 + 4 * kk + 0];
      float x1 = sX[lane * 97 + 4 * kk + 1];
      float x2 = sX[lane * 97 + 4 * kk + 2];
      float x3 = sX[lane * 97 + 4 * kk + 3];
      #pragma unroll
      for (int r = 0; r < 18; ++r) {
        float4 w4 = *reinterpret_cast<const float4*>(qkvw + wrs[r] * 96 + 4 * kk);
        a[r] = fmaf(x0, w4.x, fmaf(x1, w4.y, fmaf(x2, w4.z, fmaf(x3, w4.w, a[r]))));
      }
    }
    #pragma unroll
    for (int r = 0; r < 18; ++r) {
      int qc = wv + 4 * ((r < 6) ? r : (r < 12) ? (r - 6) : (r - 12));
      if (r < 6)       sQ[lane * 25 + qc] = a[r] * qscale;
      else if (r < 12) sK[lane * 25 + qc] = a[r];
      else             sV[lane * 25 + qc] = a[r];
    }
    __syncthreads();

    // ---- scores: 4x4 tile per thread ----
    {
      int ig = tid >> 4;            // 0..15
      int jg = tid & 15;            // 0..15
      float accS[16];
      #pragma unroll
      for (int z = 0; z < 16; ++z) accS[z] = 0.f;
      #pragma unroll 4
      for (int dd = 0; dd < 24; ++dd) {
        float q0 = sQ[(ig * 4 + 0) * 25 + dd];
        float q1 = sQ[(ig * 4 + 1) * 25 + dd];
        float q2 = sQ[(ig * 4 + 2) * 25 + dd];
        float q3 = sQ[(ig * 4 + 3) * 25 + dd];
        float k0 = sK[(jg * 4 + 0) * 25 + dd];
        float k1 = sK[(jg * 4 + 1) * 25 + dd];
        float k2 = sK[(jg * 4 + 2) * 25 + dd];
        float k3 = sK[(jg * 4 + 3) * 25 + dd];
        accS[0]  = fmaf(q0, k0, accS[0]);  accS[1]  = fmaf(q0, k1, accS[1]);
        accS[2]  = fmaf(q0, k2, accS[2]);  accS[3]  = fmaf(q0, k3, accS[3]);
        accS[4]  = fmaf(q1, k0, accS[4]);  accS[5]  = fmaf(q1, k1, accS[5]);
        accS[6]  = fmaf(q1, k2, accS[6]);  accS[7]  = fmaf(q1, k3, accS[7]);
        accS[8]  = fmaf(q2, k0, accS[8]);  accS[9]  = fmaf(q2, k1, accS[9]);
        accS[10] = fmaf(q2, k2, accS[10]); accS[11] = fmaf(q2, k3, accS[11]);
        accS[12] = fmaf(q3, k0, accS[12]); accS[13] = fmaf(q3, k1, accS[13]);
        accS[14] = fmaf(q3, k2, accS[14]); accS[15] = fmaf(q3, k3, accS[15]);
      }
      #pragma unroll
      for (int ii = 0; ii < 4; ++ii) {
        int i = ig * 4 + ii;
        int d1 = i >> 4, e1 = (i >> 2) & 3, w1 = i & 3;
        int li = slab[i];
        #pragma unroll
        for (int jj = 0; jj < 4; ++jj) {
          int j = jg * 4 + jj;
          int d2 = j >> 4, e2 = (j >> 2) & 3, w2 = j & 3;
          int ridx = (d1 - d2 + 3) * 49 + (e1 - e2 + 3) * 7 + (w1 - w2 + 3);
          float s = accS[ii * 4 + jj] + rpb[ridx * 4 + hh];
          if (li != slab[j]) s -= 100.f;
          sS[i * 65 + j] = s;
        }
      }
    }
    __syncthreads();

    // ---- softmax: 4 lanes per row ----
    {
      int i = tid >> 2, gg = tid & 3;
      float m = -1e30f;
      #pragma unroll
      for (int k = 0; k < 16; ++k) m = fmaxf(m, sS[i * 65 + gg + 4 * k]);
      m = fmaxf(m, __shfl_xor(m, 1)); m = fmaxf(m, __shfl_xor(m, 2));
      float sum = 0.f;
      #pragma unroll
      for (int k = 0; k < 16; ++k) {
        float e = expf(sS[i * 65 + gg + 4 * k] - m);
        sS[i * 65 + gg + 4 * k] = e;
        sum += e;
      }
      sum += __shfl_xor(sum, 1); sum += __shfl_xor(sum, 2);
      float inv = 1.f / sum;
      #pragma unroll
      for (int k = 0; k < 16; ++k) sS[i * 65 + gg + 4 * k] *= inv;
    }
    __syncthreads();

    // ---- PV: thread owns (i = tid>>2, 6 channels) ----
    {
      int i = tid >> 2, dg = tid & 3;
      float o0 = 0, o1 = 0, o2 = 0, o3 = 0, o4 = 0, o5 = 0;
      #pragma unroll 8
      for (int j = 0; j < 64; ++j) {
        float p = sS[i * 65 + j];
        const float* vp = &sV[j * 25 + dg * 6];
        o0 = fmaf(p, vp[0], o0); o1 = fmaf(p, vp[1], o1);
        o2 = fmaf(p, vp[2], o2); o3 = fmaf(p, vp[3], o3);
        o4 = fmaf(p, vp[4], o4); o5 = fmaf(p, vp[5], o5);
      }
      Oreg[hh * 6 + 0] = o0; Oreg[hh * 6 + 1] = o1; Oreg[hh * 6 + 2] = o2;
      Oreg[hh * 6 + 3] = o3; Oreg[hh * 6 + 4] = o4; Oreg[hh * 6 + 5] = o5;
    }
    __syncthreads();
  }

  // ---- O regs -> LDS (overlay on sU), stride 97 ----
  float* sO = sU;
  {
    int i = tid >> 2, dg = tid & 3;
    #pragma unroll
    for (int hh = 0; hh < 4; ++hh)
      #pragma unroll
      for (int dd = 0; dd < 6; ++dd)
        sO[i * 97 + hh * 24 + dg * 6 + dd] = Oreg[hh * 6 + dd];
  }
  __syncthreads();

  // ---- proj: thread owns token t=lane, 24 out channels ----
  {
    float accP[24];
    #pragma unroll
    for (int r = 0; r < 24; ++r) accP[r] = projb[wv + 4 * r];
    #pragma unroll 3
    for (int kk = 0; kk < 24; ++kk) {
      float x0 = sO[lane * 97 + 4 * kk + 0];
      float x1 = sO[lane * 97 + 4 * kk + 1];
      float x2 = sO[lane * 97 + 4 * kk + 2];
      float x3 = sO[lane * 97 + 4 * kk + 3];
      #pragma unroll
      for (int r = 0; r < 24; ++r) {
        int c = wv + 4 * r;
        float4 w4 = *reinterpret_cast<const float4*>(projw + c * 96 + 4 * kk);
        accP[r] = fmaf(x0, w4.x, fmaf(x1, w4.y, fmaf(x2, w4.z, fmaf(x3, w4.w, accP[r]))));
      }
    }
    // bounce through sX (dead) for coalesced global write
    #pragma unroll
    for (int r = 0; r < 24; ++r) sX[lane * 97 + wv + 4 * r] = accP[r];
  }
  __syncthreads();
  float* dst = yw + bn * 6144;
  #pragma unroll
  for (int it = 0; it < 24; ++it) {
    int idx = it * 256 + tid;
    int t = idx / 96;
    int c = idx - t * 96;
    dst[idx] = sX[t * 97 + c];
  }
}

// ---------------------------------------------------------------- K3
// shortcut + window-reverse+roll-back gather + LN2 + MLP (erf-GELU) +
// residual + transpose to (B,C,D,H,W).  grid 4096 = b*2048 + d*64 + h.
__global__ __launch_bounds__(256) void k3_mlp(
    const float* __restrict__ x, const float* __restrict__ yw,
    const float* __restrict__ g2, const float* __restrict__ b2,
    const float* __restrict__ fc1w, const float* __restrict__ fc1b,
    const float* __restrict__ fc2w, const float* __restrict__ fc2b,
    float* __restrict__ out)
{
  __shared__ float sX2[64 * 97];    // x2 = shortcut + attn
  __shared__ float sA[6272];        // xln(bf16) | h1(bf16) ; later sAcc(f32)
  __hip_bfloat16* xln = reinterpret_cast<__hip_bfloat16*>(sA);          // [64][98]
  __hip_bfloat16* sH1 = reinterpret_cast<__hip_bfloat16*>(sA + 3136);   // [64][98]

  int blk = blockIdx.x;
  int b = blk >> 11;
  int d = (blk >> 6) & 31;
  int h = blk & 63;
  int tid = threadIdx.x;
  int lane = tid & 63;
  int wv = tid >> 6;

  int base = (b * 96 * 32 + d) * 4096 + h * 64;
  #pragma unroll
  for (int it = 0; it < 24; ++it) {
    int idx = it * 256 + tid;
    int c = idx >> 6;
    int w = idx & 63;
    sX2[w * 97 + c] = x[base + c * 131072 + w];
  }
  __syncthreads();
  {
    int t = tid >> 2, gq = tid & 3;
    int dr = (d + 30) & 31, hr = (h + 62) & 63, wr = (t + 62) & 63;
    int widx = ((dr >> 2) << 8) | ((hr >> 2) << 4) | (wr >> 2);
    int n    = ((dr & 3) << 4) | ((hr & 3) << 2) | (wr & 3);
    const float* src = yw + (b * 2048 + widx) * 6144 + n * 96;
    #pragma unroll
    for (int k = 0; k < 24; ++k) {
      int c = gq + 4 * k;
      sX2[t * 97 + c] += src[c];
    }
  }
  __syncthreads();
  // LN2 -> xln (bf16, [64][98])
  {
    int t = tid >> 2, gq = tid & 3;
    float s1 = 0.f, s2 = 0.f;
    #pragma unroll
    for (int k = 0; k < 24; ++k) {
      float v = sX2[t * 97 + gq + 4 * k];
      s1 += v; s2 += v * v;
    }
    s1 += __shfl_xor(s1, 1); s1 += __shfl_xor(s1, 2);
    s2 += __shfl_xor(s2, 1); s2 += __shfl_xor(s2, 2);
    float mean = s1 * (1.0f / 96.0f);
    float var  = s2 * (1.0f / 96.0f) - mean * mean;
    float rstd = rsqrtf(var + 1e-5f);
    #pragma unroll
    for (int k = 0; k < 24; ++k) {
      int c = gq + 4 * k;
      float v = (sX2[t * 97 + c] - mean) * rstd * g2[c] + b2[c];
      xln[t * 98 + c] = __float2bfloat16(v);
    }
  }
  __syncthreads();

  float acc[24];
  #pragma unroll
  for (int rc = 0; rc < 24; ++rc) acc[rc] = 0.f;

  const uint32* xlnu = reinterpret_cast<const uint32*>(sA);          // [t*49 + k/2]
  const uint32* h1u  = reinterpret_cast<const uint32*>(sA + 3136);

  for (int chunk = 0; chunk < 4; ++chunk) {
    // fc1 + GELU: thread owns token t=lane, 24 j's of this 96-chunk
    {
      float a1[24];
      #pragma unroll
      for (int r = 0; r < 24; ++r) a1[r] = fc1b[chunk * 96 + wv + 4 * r];
      #pragma unroll 3
      for (int kk = 0; kk < 24; ++kk) {
        uint32 u0 = xlnu[lane * 49 + 2 * kk];
        uint32 u1 = xlnu[lane * 49 + 2 * kk + 1];
        float x0 = bf_lo(u0), x1 = bf_hi(u0), x2 = bf_lo(u1), x3 = bf_hi(u1);
        #pragma unroll
        for (int r = 0; r < 24; ++r) {
          int row = chunk * 96 + wv + 4 * r;
          float4 w4 = *reinterpret_cast<const float4*>(fc1w + row * 96 + 4 * kk);
          a1[r] = fmaf(x0, w4.x, fmaf(x1, w4.y, fmaf(x2, w4.z, fmaf(x3, w4.w, a1[r]))));
        }
      }
      #pragma unroll
      for (int r = 0; r < 24; ++r) {
        float s = a1[r];
        float gel = 0.5f * s * (1.f + erff(s * 0.7071067811865476f));
        sH1[lane * 98 + wv + 4 * r] = __float2bfloat16(gel);
      }
    }
    __syncthreads();
    // fc2 accumulate: thread owns token t=lane, 24 out channels
    {
      #pragma unroll 3
      for (int kk = 0; kk < 24; ++kk) {
        uint32 u0 = h1u[lane * 49 + 2 * kk];
        uint32 u1 = h1u[lane * 49 + 2 * kk + 1];
        float v0 = bf_lo(u0), v1 = bf_hi(u0), v2 = bf_lo(u1), v3 = bf_hi(u1);
        #pragma unroll
        for (int rc = 0; rc < 24; ++rc) {
          int c = wv + 4 * rc;
          float4 w4 = *reinterpret_cast<const float4*>(fc2w + c * 384 + chunk * 96 + 4 * kk);
          acc[rc] = fmaf(v0, w4.x, fmaf(v1, w4.y, fmaf(v2, w4.z, fmaf(v3, w4.w, acc[rc]))));
        }
      }
    }
    __syncthreads();
  }
  // acc -> sA (fp32, stride 97); xln/h1 dead now
  float* sAcc = sA;
  #pragma unroll
  for (int rc = 0; rc < 24; ++rc) sAcc[lane * 97 + wv + 4 * rc] = acc[rc];
  __syncthreads();
  #pragma unroll
  for (int it = 0; it < 24; ++it) {
    int idx = it * 256 + tid;
    int c = idx >> 6;
    int w = idx & 63;
    float v = sX2[w * 97 + c] + sAcc[w * 97 + c] + fc2b[c];
    out[base + c * 131072 + w] = v;
  }
}

// ---------------------------------------------------------------- launch
extern "C" void kernel_launch(void* const* d_in, const int* in_sizes, int n_in,
                              void* d_out, int out_size, void* d_ws, size_t ws_size,
                              hipStream_t stream) {
  (void)in_sizes; (void)n_in; (void)out_size; (void)ws_size;
  const float* x     = (const float*)d_in[0];
  const float* g1    = (const float*)d_in[1];
  const float* b1    = (const float*)d_in[2];
  const float* qkvw  = (const float*)d_in[3];
  const float* qkvb  = (const float*)d_in[4];
  const float* rpb   = (const float*)d_in[5];
  const float* projw = (const float*)d_in[6];
  const float* projb = (const float*)d_in[7];
  const float* g2    = (const float*)d_in[8];
  const float* b2    = (const float*)d_in[9];
  const float* fc1w  = (const float*)d_in[10];
  const float* fc1b  = (const float*)d_in[11];
  const float* fc2w  = (const float*)d_in[12];
  const float* fc2b  = (const float*)d_in[13];
  float* out = (float*)d_out;

  float* xw = (float*)d_ws;          // 262144*96 floats = 100.7 MB
  float* yw = xw + 25165824;         // another 100.7 MB

  k1_ln_part<<<4096, 256, 0, stream>>>(x, g1, b1, xw);
  k2_attn  <<<4096, 256, 0, stream>>>(xw, qkvw, qkvb, rpb, projw, projb, yw);
  k3_mlp   <<<4096, 256, 0, stream>>>(x, yw, g2, b2, fc1w, fc1b, fc2w, fc2b, out);
}

// Round 2
// 2135.055 us; speedup vs baseline: 2.1424x; 2.1424x over previous
//
#include <hip/hip_runtime.h>
#include <hip/hip_bf16.h>

// Swin-3D block. K1/K2 fp32 SIMT (unchanged), K3 MLP on bf16 MFMA.
// B=2, C=96, D=32, H=64, W=64, WS=4, SHIFT=2, HEADS=4, hd=24
// tokens T = 262144, windows Bn = 4096, N = 64 tokens/window.

typedef unsigned int uint32;
typedef unsigned short ushort16;
typedef __attribute__((ext_vector_type(8))) short bfrag;   // 8 bf16 (4 VGPRs)
typedef __attribute__((ext_vector_type(4))) float ffrag;   // 4 fp32 acc

__device__ __forceinline__ float bf_lo(uint32 u) { return __uint_as_float(u << 16); }
__device__ __forceinline__ float bf_hi(uint32 u) { return __uint_as_float(u & 0xffff0000u); }

__device__ __forceinline__ unsigned short f2bf(float v) {
  __hip_bfloat16 h = __float2bfloat16(v);
  return *reinterpret_cast<unsigned short*>(&h);
}

// ---------------------------------------------------------------- K0
// fp32 -> bf16 weight pre-conversion (fc1w, fc2w: 36864 elems each).
__global__ __launch_bounds__(256) void k0_conv(
    const float* __restrict__ w1, const float* __restrict__ w2,
    unsigned short* __restrict__ o1, unsigned short* __restrict__ o2)
{
  int i = blockIdx.x * 256 + threadIdx.x;   // grid 144 -> 36864 exactly
  o1[i] = f2bf(w1[i]);
  o2[i] = f2bf(w2[i]);
}

// ---------------------------------------------------------------- K1
// LN1 + roll(-2,-2,-2) + 4x4x4 window partition.
__global__ __launch_bounds__(256) void k1_ln_part(
    const float* __restrict__ x, const float* __restrict__ g1,
    const float* __restrict__ b1, float* __restrict__ xw)
{
  __shared__ float sX[64 * 97];
  int blk = blockIdx.x;
  int b = blk >> 11;
  int d = (blk >> 6) & 31;
  int h = blk & 63;
  int tid = threadIdx.x;
  int base = (b * 96 * 32 + d) * 4096 + h * 64;   // + c*131072 + w
  #pragma unroll
  for (int it = 0; it < 24; ++it) {
    int idx = it * 256 + tid;
    int c = idx >> 6;
    int w = idx & 63;
    sX[w * 97 + c] = x[base + c * 131072 + w];
  }
  __syncthreads();
  int t = tid >> 2, gq = tid & 3;
  float s1 = 0.f, s2 = 0.f;
  #pragma unroll
  for (int k = 0; k < 24; ++k) {
    float v = sX[t * 97 + gq + 4 * k];
    s1 += v; s2 += v * v;
  }
  s1 += __shfl_xor(s1, 1); s1 += __shfl_xor(s1, 2);
  s2 += __shfl_xor(s2, 1); s2 += __shfl_xor(s2, 2);
  float mean = s1 * (1.0f / 96.0f);
  float var  = s2 * (1.0f / 96.0f) - mean * mean;
  float rstd = rsqrtf(var + 1e-5f);
  int dr = (d + 30) & 31, hr = (h + 62) & 63, wr = (t + 62) & 63;
  int widx = ((dr >> 2) << 8) | ((hr >> 2) << 4) | (wr >> 2);
  int n    = ((dr & 3) << 4) | ((hr & 3) << 2) | (wr & 3);
  int obase = (b * 2048 + widx) * 6144 + n * 96;
  #pragma unroll
  for (int k = 0; k < 24; ++k) {
    int c = gq + 4 * k;
    xw[obase + c] = (sX[t * 97 + c] - mean) * rstd * g1[c] + b1[c];
  }
}

// ---------------------------------------------------------------- K2
// Per-window fused: QKV -> scores + bias + mask -> softmax -> PV -> proj.
__global__ __launch_bounds__(256) void k2_attn(
    const float* __restrict__ xw, const float* __restrict__ qkvw,
    const float* __restrict__ qkvb, const float* __restrict__ rpb,
    const float* __restrict__ projw, const float* __restrict__ projb,
    float* __restrict__ yw)
{
  __shared__ float sX[64 * 97];
  __shared__ float sU[8960];
  __shared__ int slab[64];
  float* sQ = sU;                   // [64][25]
  float* sK = sU + 1600;
  float* sV = sU + 3200;
  float* sS = sU + 4800;            // [64][65]

  int bn = blockIdx.x;
  int widx = bn & 2047;
  int tid = threadIdx.x;
  int lane = tid & 63;
  int wv = tid >> 6;

  const float* xrow = xw + bn * 6144;
  #pragma unroll
  for (int it = 0; it < 24; ++it) {
    int idx = it * 256 + tid;
    int t = idx / 96;
    int c = idx - t * 96;
    sX[t * 97 + c] = xrow[idx];
  }
  if (tid < 64) {
    int dw = widx >> 8, hw = (widx >> 4) & 15, ww = widx & 15;
    int d1 = tid >> 4, e1 = (tid >> 2) & 3, w1 = tid & 3;
    int ld = (dw == 7)  ? ((d1 >> 1) + 1) : 0;
    int lh = (hw == 15) ? ((e1 >> 1) + 1) : 0;
    int lw = (ww == 15) ? ((w1 >> 1) + 1) : 0;
    slab[tid] = ld * 9 + lh * 3 + lw;
  }
  __syncthreads();

  float Oreg[24];
  const float qscale = 0.20412414523193154f;

  #pragma unroll
  for (int hh = 0; hh < 4; ++hh) {
    int wrs[18];
    #pragma unroll
    for (int r = 0; r < 18; ++r)
      wrs[r] = (r < 6)  ? (hh * 24 + wv + 4 * r)
             : (r < 12) ? (96 + hh * 24 + wv + 4 * (r - 6))
                        : (192 + hh * 24 + wv + 4 * (r - 12));
    float a[18];
    #pragma unroll
    for (int r = 0; r < 18; ++r) a[r] = qkvb[wrs[r]];
    #pragma unroll 3
    for (int kk = 0; kk < 24; ++kk) {
      float x0 = sX[lane * 97 + 4 * kk + 0];
      float x1 = sX[lane * 97 + 4 * kk + 1];
      float x2 = sX[lane * 97 + 4 * kk + 2];
      float x3 = sX[lane * 97 + 4 * kk + 3];
      #pragma unroll
      for (int r = 0; r < 18; ++r) {
        float4 w4 = *reinterpret_cast<const float4*>(qkvw + wrs[r] * 96 + 4 * kk);
        a[r] = fmaf(x0, w4.x, fmaf(x1, w4.y, fmaf(x2, w4.z, fmaf(x3, w4.w, a[r]))));
      }
    }
    #pragma unroll
    for (int r = 0; r < 18; ++r) {
      int qc = wv + 4 * ((r < 6) ? r : (r < 12) ? (r - 6) : (r - 12));
      if (r < 6)       sQ[lane * 25 + qc] = a[r] * qscale;
      else if (r < 12) sK[lane * 25 + qc] = a[r];
      else             sV[lane * 25 + qc] = a[r];
    }
    __syncthreads();

    {
      int ig = tid >> 4;
      int jg = tid & 15;
      float accS[16];
      #pragma unroll
      for (int z = 0; z < 16; ++z) accS[z] = 0.f;
      #pragma unroll 4
      for (int dd = 0; dd < 24; ++dd) {
        float q0 = sQ[(ig * 4 + 0) * 25 + dd];
        float q1 = sQ[(ig * 4 + 1) * 25 + dd];
        float q2 = sQ[(ig * 4 + 2) * 25 + dd];
        float q3 = sQ[(ig * 4 + 3) * 25 + dd];
        float k0 = sK[(jg * 4 + 0) * 25 + dd];
        float k1 = sK[(jg * 4 + 1) * 25 + dd];
        float k2 = sK[(jg * 4 + 2) * 25 + dd];
        float k3 = sK[(jg * 4 + 3) * 25 + dd];
        accS[0]  = fmaf(q0, k0, accS[0]);  accS[1]  = fmaf(q0, k1, accS[1]);
        accS[2]  = fmaf(q0, k2, accS[2]);  accS[3]  = fmaf(q0, k3, accS[3]);
        accS[4]  = fmaf(q1, k0, accS[4]);  accS[5]  = fmaf(q1, k1, accS[5]);
        accS[6]  = fmaf(q1, k2, accS[6]);  accS[7]  = fmaf(q1, k3, accS[7]);
        accS[8]  = fmaf(q2, k0, accS[8]);  accS[9]  = fmaf(q2, k1, accS[9]);
        accS[10] = fmaf(q2, k2, accS[10]); accS[11] = fmaf(q2, k3, accS[11]);
        accS[12] = fmaf(q3, k0, accS[12]); accS[13] = fmaf(q3, k1, accS[13]);
        accS[14] = fmaf(q3, k2, accS[14]); accS[15] = fmaf(q3, k3, accS[15]);
      }
      #pragma unroll
      for (int ii = 0; ii < 4; ++ii) {
        int i = ig * 4 + ii;
        int d1 = i >> 4, e1 = (i >> 2) & 3, w1 = i & 3;
        int li = slab[i];
        #pragma unroll
        for (int jj = 0; jj < 4; ++jj) {
          int j = jg * 4 + jj;
          int d2 = j >> 4, e2 = (j >> 2) & 3, w2 = j & 3;
          int ridx = (d1 - d2 + 3) * 49 + (e1 - e2 + 3) * 7 + (w1 - w2 + 3);
          float s = accS[ii * 4 + jj] + rpb[ridx * 4 + hh];
          if (li != slab[j]) s -= 100.f;
          sS[i * 65 + j] = s;
        }
      }
    }
    __syncthreads();

    {
      int i = tid >> 2, gg = tid & 3;
      float m = -1e30f;
      #pragma unroll
      for (int k = 0; k < 16; ++k) m = fmaxf(m, sS[i * 65 + gg + 4 * k]);
      m = fmaxf(m, __shfl_xor(m, 1)); m = fmaxf(m, __shfl_xor(m, 2));
      float sum = 0.f;
      #pragma unroll
      for (int k = 0; k < 16; ++k) {
        float e = expf(sS[i * 65 + gg + 4 * k] - m);
        sS[i * 65 + gg + 4 * k] = e;
        sum += e;
      }
      sum += __shfl_xor(sum, 1); sum += __shfl_xor(sum, 2);
      float inv = 1.f / sum;
      #pragma unroll
      for (int k = 0; k < 16; ++k) sS[i * 65 + gg + 4 * k] *= inv;
    }
    __syncthreads();

    {
      int i = tid >> 2, dg = tid & 3;
      float o0 = 0, o1 = 0, o2 = 0, o3 = 0, o4 = 0, o5 = 0;
      #pragma unroll 8
      for (int j = 0; j < 64; ++j) {
        float p = sS[i * 65 + j];
        const float* vp = &sV[j * 25 + dg * 6];
        o0 = fmaf(p, vp[0], o0); o1 = fmaf(p, vp[1], o1);
        o2 = fmaf(p, vp[2], o2); o3 = fmaf(p, vp[3], o3);
        o4 = fmaf(p, vp[4], o4); o5 = fmaf(p, vp[5], o5);
      }
      Oreg[hh * 6 + 0] = o0; Oreg[hh * 6 + 1] = o1; Oreg[hh * 6 + 2] = o2;
      Oreg[hh * 6 + 3] = o3; Oreg[hh * 6 + 4] = o4; Oreg[hh * 6 + 5] = o5;
    }
    __syncthreads();
  }

  float* sO = sU;
  {
    int i = tid >> 2, dg = tid & 3;
    #pragma unroll
    for (int hh = 0; hh < 4; ++hh)
      #pragma unroll
      for (int dd = 0; dd < 6; ++dd)
        sO[i * 97 + hh * 24 + dg * 6 + dd] = Oreg[hh * 6 + dd];
  }
  __syncthreads();

  {
    float accP[24];
    #pragma unroll
    for (int r = 0; r < 24; ++r) accP[r] = projb[wv + 4 * r];
    #pragma unroll 3
    for (int kk = 0; kk < 24; ++kk) {
      float x0 = sO[lane * 97 + 4 * kk + 0];
      float x1 = sO[lane * 97 + 4 * kk + 1];
      float x2 = sO[lane * 97 + 4 * kk + 2];
      float x3 = sO[lane * 97 + 4 * kk + 3];
      #pragma unroll
      for (int r = 0; r < 24; ++r) {
        int c = wv + 4 * r;
        float4 w4 = *reinterpret_cast<const float4*>(projw + c * 96 + 4 * kk);
        accP[r] = fmaf(x0, w4.x, fmaf(x1, w4.y, fmaf(x2, w4.z, fmaf(x3, w4.w, accP[r]))));
      }
    }
    #pragma unroll
    for (int r = 0; r < 24; ++r) sX[lane * 97 + wv + 4 * r] = accP[r];
  }
  __syncthreads();
  float* dst = yw + bn * 6144;
  #pragma unroll
  for (int it = 0; it < 24; ++it) {
    int idx = it * 256 + tid;
    int t = idx / 96;
    int c = idx - t * 96;
    dst[idx] = sX[t * 97 + c];
  }
}

// ---------------------------------------------------------------- K3
// shortcut + window-reverse gather + LN2 + MLP (bf16 MFMA) + residual +
// transpose store.  grid 4096 = b*2048 + d*64 + h, block 256 (4 waves).
// Wave w owns token rows [16w, 16w+16): gather/LN2/fc1/GELU/fc2 are all
// wave-local in rows -> no inner barriers.
__global__ __launch_bounds__(256) void k3_mlp(
    const float* __restrict__ x, const float* __restrict__ yw,
    const float* __restrict__ g2, const float* __restrict__ b2,
    const unsigned short* __restrict__ w1, const float* __restrict__ fc1b,
    const unsigned short* __restrict__ w2, const float* __restrict__ fc2b,
    float* __restrict__ out)
{
  __shared__ float sX2[64 * 97];          // 24832 B, persists for residual
  __shared__ unsigned short sB[2][64 * 104];  // xln | h1 (13312 B each)
  unsigned short* xln = sB[0];
  unsigned short* h1  = sB[1];

  int blk = blockIdx.x;
  int b = blk >> 11;
  int d = (blk >> 6) & 31;
  int h = blk & 63;
  int tid = threadIdx.x;
  int lane = tid & 63;
  int wv = tid >> 6;
  int l15 = lane & 15, l16 = lane >> 4;

  int base = (b * 96 * 32 + d) * 4096 + h * 64;
  #pragma unroll
  for (int it = 0; it < 24; ++it) {
    int idx = it * 256 + tid;
    int c = idx >> 6;
    int w = idx & 63;
    sX2[w * 97 + c] = x[base + c * 131072 + w];
  }
  __syncthreads();

  // gather attn-out (wave-local rows t = tid>>2)
  {
    int t = tid >> 2, gq = tid & 3;
    int dr = (d + 30) & 31, hr = (h + 62) & 63, wr = (t + 62) & 63;
    int widx = ((dr >> 2) << 8) | ((hr >> 2) << 4) | (wr >> 2);
    int n    = ((dr & 3) << 4) | ((hr & 3) << 2) | (wr & 3);
    const float* src = yw + (b * 2048 + widx) * 6144 + n * 96;
    #pragma unroll
    for (int k = 0; k < 24; ++k) {
      int c = gq + 4 * k;
      sX2[t * 97 + c] += src[c];
    }
  }
  // LN2 -> xln bf16 [64][104] (wave-local)
  {
    int t = tid >> 2, gq = tid & 3;
    float s1 = 0.f, s2 = 0.f;
    #pragma unroll
    for (int k = 0; k < 24; ++k) {
      float v = sX2[t * 97 + gq + 4 * k];
      s1 += v; s2 += v * v;
    }
    s1 += __shfl_xor(s1, 1); s1 += __shfl_xor(s1, 2);
    s2 += __shfl_xor(s2, 1); s2 += __shfl_xor(s2, 2);
    float mean = s1 * (1.0f / 96.0f);
    float var  = s2 * (1.0f / 96.0f) - mean * mean;
    float rstd = rsqrtf(var + 1e-5f);
    #pragma unroll
    for (int k = 0; k < 24; ++k) {
      int c = gq + 4 * k;
      float v = (sX2[t * 97 + c] - mean) * rstd * g2[c] + b2[c];
      xln[t * 104 + c] = f2bf(v);
    }
  }

  // ---- MLP: 4 hidden chunks of 96, MFMA 16x16x32 bf16 ----
  int arow = (16 * wv + l15) * 104 + l16 * 8;   // A-frag elem offset

  ffrag acc2[6];
  #pragma unroll
  for (int nt = 0; nt < 6; ++nt) {
    float bias = fc2b[nt * 16 + l15];
    acc2[nt] = (ffrag){bias, bias, bias, bias};
  }

  for (int cc = 0; cc < 4; ++cc) {
    // fc1 + GELU -> h1 (wave-local rows)
    bfrag a0 = *reinterpret_cast<const bfrag*>(&xln[arow + 0]);
    bfrag a1 = *reinterpret_cast<const bfrag*>(&xln[arow + 32]);
    bfrag a2 = *reinterpret_cast<const bfrag*>(&xln[arow + 64]);
    const unsigned short* w1p = w1 + (cc * 96 + l15) * 96 + l16 * 8;
    #pragma unroll
    for (int nt = 0; nt < 6; ++nt) {
      float bias = fc1b[cc * 96 + nt * 16 + l15];
      ffrag acc = (ffrag){bias, bias, bias, bias};
      bfrag b0 = *reinterpret_cast<const bfrag*>(w1p + nt * 16 * 96 + 0);
      bfrag b1 = *reinterpret_cast<const bfrag*>(w1p + nt * 16 * 96 + 32);
      bfrag bb2 = *reinterpret_cast<const bfrag*>(w1p + nt * 16 * 96 + 64);
      acc = __builtin_amdgcn_mfma_f32_16x16x32_bf16(a0, b0, acc, 0, 0, 0);
      acc = __builtin_amdgcn_mfma_f32_16x16x32_bf16(a1, b1, acc, 0, 0, 0);
      acc = __builtin_amdgcn_mfma_f32_16x16x32_bf16(a2, bb2, acc, 0, 0, 0);
      #pragma unroll
      for (int r = 0; r < 4; ++r) {
        float s = acc[r];
        float gel = 0.5f * s * (1.f + erff(s * 0.7071067811865476f));
        h1[(16 * wv + l16 * 4 + r) * 104 + nt * 16 + l15] = f2bf(gel);
      }
    }
    // fc2 accumulate (reads h1 wave-locally)
    bfrag c0 = *reinterpret_cast<const bfrag*>(&h1[arow + 0]);
    bfrag c1 = *reinterpret_cast<const bfrag*>(&h1[arow + 32]);
    bfrag c2 = *reinterpret_cast<const bfrag*>(&h1[arow + 64]);
    const unsigned short* w2p = w2 + l15 * 384 + cc * 96 + l16 * 8;
    #pragma unroll
    for (int nt = 0; nt < 6; ++nt) {
      bfrag d0 = *reinterpret_cast<const bfrag*>(w2p + nt * 16 * 384 + 0);
      bfrag d1 = *reinterpret_cast<const bfrag*>(w2p + nt * 16 * 384 + 32);
      bfrag d2 = *reinterpret_cast<const bfrag*>(w2p + nt * 16 * 384 + 64);
      acc2[nt] = __builtin_amdgcn_mfma_f32_16x16x32_bf16(c0, d0, acc2[nt], 0, 0, 0);
      acc2[nt] = __builtin_amdgcn_mfma_f32_16x16x32_bf16(c1, d1, acc2[nt], 0, 0, 0);
      acc2[nt] = __builtin_amdgcn_mfma_f32_16x16x32_bf16(c2, d2, acc2[nt], 0, 0, 0);
    }
  }

  // all waves done with xln/h1 -> overlay fp32 sAcc [64][97]
  __syncthreads();
  float* sAcc = reinterpret_cast<float*>(sB);
  #pragma unroll
  for (int nt = 0; nt < 6; ++nt)
    #pragma unroll
    for (int r = 0; r < 4; ++r)
      sAcc[(16 * wv + l16 * 4 + r) * 97 + nt * 16 + l15] = acc2[nt][r];
  __syncthreads();

  #pragma unroll
  for (int it = 0; it < 24; ++it) {
    int idx = it * 256 + tid;
    int c = idx >> 6;
    int w = idx & 63;
    out[base + c * 131072 + w] = sX2[w * 97 + c] + sAcc[w * 97 + c];
  }
}

// ---------------------------------------------------------------- launch
extern "C" void kernel_launch(void* const* d_in, const int* in_sizes, int n_in,
                              void* d_out, int out_size, void* d_ws, size_t ws_size,
                              hipStream_t stream) {
  (void)in_sizes; (void)n_in; (void)out_size; (void)ws_size;
  const float* x     = (const float*)d_in[0];
  const float* g1    = (const float*)d_in[1];
  const float* b1    = (const float*)d_in[2];
  const float* qkvw  = (const float*)d_in[3];
  const float* qkvb  = (const float*)d_in[4];
  const float* rpb   = (const float*)d_in[5];
  const float* projw = (const float*)d_in[6];
  const float* projb = (const float*)d_in[7];
  const float* g2    = (const float*)d_in[8];
  const float* b2    = (const float*)d_in[9];
  const float* fc1w  = (const float*)d_in[10];
  const float* fc1b  = (const float*)d_in[11];
  const float* fc2w  = (const float*)d_in[12];
  const float* fc2b  = (const float*)d_in[13];
  float* out = (float*)d_out;

  float* xw = (float*)d_ws;               // 100.7 MB
  float* yw = xw + 25165824;              // 100.7 MB
  unsigned short* w1b = (unsigned short*)(yw + 25165824);   // 73728 B
  unsigned short* w2b = w1b + 36864;                        // 73728 B

  k0_conv  <<<144,  256, 0, stream>>>(fc1w, fc2w, w1b, w2b);
  k1_ln_part<<<4096, 256, 0, stream>>>(x, g1, b1, xw);
  k2_attn  <<<4096, 256, 0, stream>>>(xw, qkvw, qkvb, rpb, projw, projb, yw);
  k3_mlp   <<<4096, 256, 0, stream>>>(x, yw, g2, b2, w1b, fc1b, w2b, fc2b, out);
}